// Round 7
// baseline (404.297 us; speedup 1.0000x reference)
//
#include <hip/hip_runtime.h>

#define N_NODES 50000
#define N_EDGES 800000
#define N_GRAPHS 512
#define DIM 128

#define BW_LOG 9
#define BWID 512                                  // nodes per bucket
#define NB ((N_NODES + BWID - 1) / BWID)          // 98
#define CHUNK 4096                                // edges per phase-A block
#define NCHUNK ((N_EDGES + CHUNK - 1) / CHUNK)    // 196

typedef unsigned int uint;
typedef unsigned short ushort;

// bf16 helpers (RNE pack, cheap unpack)
__device__ __forceinline__ ushort f2bf(float f) {
    uint u = __float_as_uint(f);
    return (ushort)((u + 0x7fffu + ((u >> 16) & 1u)) >> 16);
}
__device__ __forceinline__ float bflo(uint p) { return __uint_as_float(p << 16); }
__device__ __forceinline__ float bfhi(uint p) { return __uint_as_float(p & 0xffff0000u); }

// ---------------- CSR build: bucket-sorted, write-amplification-free ----------------

__global__ __launch_bounds__(256) void bhist_k(const int* __restrict__ dst,
                                               int* __restrict__ bcnt_pad, int e) {
    __shared__ int h[NB];
    int t = threadIdx.x;
    for (int i = t; i < NB; i += 256) h[i] = 0;
    __syncthreads();
    int base = blockIdx.x * CHUNK;
    for (int i = t; i < CHUNK; i += 256) {
        int idx = base + i;
        if (idx < e) atomicAdd(&h[dst[idx] >> BW_LOG], 1);
    }
    __syncthreads();
    for (int i = t; i < NB; i += 256)
        if (h[i]) atomicAdd(&bcnt_pad[i << 4], h[i]);
}

__global__ void bscan_k(const int* __restrict__ bcnt_pad, int* __restrict__ bbase,
                        int* __restrict__ bcur_pad) {
    if (threadIdx.x == 0) {
        int run = 0;
        for (int b = 0; b < NB; b++) {
            bbase[b] = run;
            bcur_pad[b << 4] = run;
            run += bcnt_pad[b << 4];
        }
        bbase[NB] = run;
    }
}

// packed record: (src << 9) | (dst & 511)
__global__ __launch_bounds__(256) void bscat_k(const int* __restrict__ src,
                                               const int* __restrict__ dst,
                                               int* __restrict__ bcur_pad,
                                               uint* __restrict__ stage, int e) {
    __shared__ int h[NB];
    __shared__ int bb[NB];
    __shared__ int lc[NB];
    int t = threadIdx.x;
    for (int i = t; i < NB; i += 256) h[i] = 0;
    __syncthreads();
    int base = blockIdx.x * CHUNK;
    for (int i = t; i < CHUNK; i += 256) {
        int idx = base + i;
        if (idx < e) atomicAdd(&h[dst[idx] >> BW_LOG], 1);
    }
    __syncthreads();
    for (int i = t; i < NB; i += 256) {
        int c = h[i];
        bb[i] = c ? atomicAdd(&bcur_pad[i << 4], c) : 0;
        lc[i] = 0;
    }
    __syncthreads();
    for (int i = t; i < CHUNK; i += 256) {
        int idx = base + i;
        if (idx < e) {
            int d = dst[idx];
            int b = d >> BW_LOG;
            int r = atomicAdd(&lc[b], 1);
            stage[bb[b] + r] = ((uint)src[idx] << BW_LOG) | (uint)(d & (BWID - 1));
        }
    }
}

__global__ __launch_bounds__(256) void csr_k(const uint* __restrict__ stage,
                                             const int* __restrict__ bbase,
                                             int* __restrict__ row_ptr,
                                             float* __restrict__ dis,
                                             int* __restrict__ col) {
    __shared__ int hist[BWID];
    __shared__ int excl[BWID];
    __shared__ int ws[256];
    int b = blockIdx.x, t = threadIdx.x;
    int beg = bbase[b], end = bbase[b + 1];
    for (int i = t; i < BWID; i += 256) hist[i] = 0;
    __syncthreads();
    for (int i = beg + t; i < end; i += 256)
        atomicAdd(&hist[stage[i] & (BWID - 1)], 1);
    __syncthreads();
    int s = hist[2 * t] + hist[2 * t + 1];
    ws[t] = s;
    __syncthreads();
    for (int o = 1; o < 256; o <<= 1) {
        int v = ws[t];
        int add = (t >= o) ? ws[t - o] : 0;
        __syncthreads();
        ws[t] = v + add;
        __syncthreads();
    }
    int pre = (t == 0) ? 0 : ws[t - 1];
    excl[2 * t] = pre;
    excl[2 * t + 1] = pre + hist[2 * t];
    __syncthreads();
    int node0 = b * BWID;
    for (int i = t; i < BWID; i += 256) {
        int node = node0 + i;
        if (node < N_NODES) {
            row_ptr[node] = beg + excl[i];
            dis[node] = rsqrtf((float)(hist[i] + 1));   // +1 = self-loop
        } else if (node == N_NODES) {
            row_ptr[node] = beg + excl[i];
        }
    }
    __syncthreads();
    for (int i = t; i < BWID; i += 256) hist[i] = excl[i];
    __syncthreads();
    for (int i = beg + t; i < end; i += 256) {
        uint p = stage[i];
        int d9 = p & (BWID - 1);
        int r = atomicAdd(&hist[d9], 1);
        col[beg + r] = (int)(p >> BW_LOG);
    }
}

// ---------------- dense GEMM: H[n x 128](bf16) = X[n x 128] @ W[128 x 128] ----------------

#define GEMM_ROWS 32

template <typename TIn>
__global__ __launch_bounds__(256) void gemm_k(const TIn* __restrict__ X,
                                              const float* __restrict__ W,
                                              ushort* __restrict__ H, int n) {
    __shared__ float Ws[64 * 128];          // 32 KB
    __shared__ float Xs[GEMM_ROWS * 128];   // 16 KB

    int t = threadIdx.x;
    int row0 = blockIdx.x * GEMM_ROWS;

    for (int i = t; i < GEMM_ROWS * 32; i += 256) {
        int r = i >> 5, q = i & 31;
        float4 v = make_float4(0.f, 0.f, 0.f, 0.f);
        if (row0 + r < n) {
            if constexpr (sizeof(TIn) == 4) {
                v = ((const float4*)X)[(size_t)(row0 + r) * 32 + q];
            } else {
                uint2 p = ((const uint2*)X)[(size_t)(row0 + r) * 32 + q];
                v = make_float4(bflo(p.x), bfhi(p.x), bflo(p.y), bfhi(p.y));
            }
        }
        ((float4*)Xs)[i] = v;
    }

    int tc = t & 31, tr = t >> 5;
    int j0 = tc * 4, r0 = tr * 4;
    float acc[4][4];
#pragma unroll
    for (int a = 0; a < 4; a++)
#pragma unroll
        for (int b = 0; b < 4; b++) acc[a][b] = 0.f;

    for (int kp = 0; kp < 2; kp++) {
        int k0 = kp * 64;
        __syncthreads();
        for (int i = t; i < 64 * 32; i += 256)
            ((float4*)Ws)[i] = ((const float4*)W)[k0 * 32 + i];
        __syncthreads();
#pragma unroll 4
        for (int k = 0; k < 64; k++) {
            float4 wv = *(const float4*)(Ws + k * 128 + j0);
#pragma unroll
            for (int a = 0; a < 4; a++) {
                float xv = Xs[(r0 + a) * 128 + k0 + k];
                acc[a][0] += xv * wv.x;
                acc[a][1] += xv * wv.y;
                acc[a][2] += xv * wv.z;
                acc[a][3] += xv * wv.w;
            }
        }
    }

#pragma unroll
    for (int a = 0; a < 4; a++) {
        int row = row0 + r0 + a;
        if (row < n) {
            uint o0 = (uint)f2bf(acc[a][0]) | ((uint)f2bf(acc[a][1]) << 16);
            uint o1 = (uint)f2bf(acc[a][2]) | ((uint)f2bf(acc[a][3]) << 16);
            *(uint2*)(H + (size_t)row * DIM + j0) = make_uint2(o0, o1);
        }
    }
}

// ---------------- CSR aggregation, XCD-pinned feature chunks ----------------
// DIM split into 4 chunks of 32 features (64B = one cache line per gather).
// chunk c pinned to XCDs {2c, 2c+1} via blockIdx%8 round-robin -> each XCD's
// gather working set is 50000*64B = 3.2MB, fits its 4MB L2.
// 8 lanes per node; per edge each 8-lane group reads exactly one 64B line.
// Self-loop analytic: acc init = dis[node]*h[node]; final scale by dis[node].

#define AGG_NPB 32                                   // nodes per block (256/8)
#define N_HALF (N_NODES / 2)                         // 25000
#define AGG_G ((N_HALF + AGG_NPB - 1) / AGG_NPB)     // 782

__global__ __launch_bounds__(256) void agg_k(const ushort* __restrict__ H,
                                             const int* __restrict__ row_ptr,
                                             const int* __restrict__ col,
                                             const float* __restrict__ dis,
                                             const float* __restrict__ bias,
                                             ushort* __restrict__ Out) {
    int g    = blockIdx.x >> 3;
    int xcd  = blockIdx.x & 7;
    int chunk  = xcd >> 1;
    int parity = xcd & 1;
    int node = parity * N_HALF + g * AGG_NPB + (threadIdx.x >> 3);
    int bound = N_HALF + parity * (N_NODES - N_HALF);
    if (node >= bound) return;
    int l8 = threadIdx.x & 7;
    int f0 = chunk * 32 + l8 * 4;                    // 4 features per lane
    const ushort* Hc = H + f0;

    float dn = dis[node];
    uint2 pw = *(const uint2*)(Hc + (size_t)node * DIM);   // self-loop line
    float a0 = dn * bflo(pw.x), a1 = dn * bfhi(pw.x);
    float a2 = dn * bflo(pw.y), a3 = dn * bfhi(pw.y);

    int beg = row_ptr[node], end = row_ptr[node + 1];
    int e = beg;
    for (; e + 3 < end; e += 4) {
        int c0 = col[e], c1 = col[e + 1], c2 = col[e + 2], c3 = col[e + 3];
        float w0 = dis[c0], w1 = dis[c1], w2 = dis[c2], w3 = dis[c3];
        uint2 p0 = *(const uint2*)(Hc + (size_t)c0 * DIM);
        uint2 p1 = *(const uint2*)(Hc + (size_t)c1 * DIM);
        uint2 p2 = *(const uint2*)(Hc + (size_t)c2 * DIM);
        uint2 p3 = *(const uint2*)(Hc + (size_t)c3 * DIM);
        a0 += w0 * bflo(p0.x) + w1 * bflo(p1.x) + w2 * bflo(p2.x) + w3 * bflo(p3.x);
        a1 += w0 * bfhi(p0.x) + w1 * bfhi(p1.x) + w2 * bfhi(p2.x) + w3 * bfhi(p3.x);
        a2 += w0 * bflo(p0.y) + w1 * bflo(p1.y) + w2 * bflo(p2.y) + w3 * bflo(p3.y);
        a3 += w0 * bfhi(p0.y) + w1 * bfhi(p1.y) + w2 * bfhi(p2.y) + w3 * bfhi(p3.y);
    }
    for (; e < end; e++) {
        int c = col[e];
        float w = dis[c];
        uint2 p = *(const uint2*)(Hc + (size_t)c * DIM);
        a0 += w * bflo(p.x);
        a1 += w * bfhi(p.x);
        a2 += w * bflo(p.y);
        a3 += w * bfhi(p.y);
    }
    a0 = fmaxf(a0 * dn + bias[f0], 0.f);
    a1 = fmaxf(a1 * dn + bias[f0 + 1], 0.f);
    a2 = fmaxf(a2 * dn + bias[f0 + 2], 0.f);
    a3 = fmaxf(a3 * dn + bias[f0 + 3], 0.f);
    uint o0 = (uint)f2bf(a0) | ((uint)f2bf(a1) << 16);
    uint o1 = (uint)f2bf(a2) | ((uint)f2bf(a3) << 16);
    *(uint2*)(Out + (size_t)node * DIM + f0) = make_uint2(o0, o1);
}

// ---------------- global add pool (batch_vec sorted, bf16 in, fp32 out) ----------------

__global__ void pool_k(const ushort* __restrict__ H, const int* __restrict__ batch,
                       float* Out, int n) {
    int d = threadIdx.x;
    int n0 = blockIdx.x * 64;
    int gcur = -1;
    float s = 0.f;
    for (int i = 0; i < 64; i++) {
        int node = n0 + i;
        if (node >= n) break;
        int g = batch[node];
        if (g != gcur) {
            if (gcur >= 0) atomicAdd(&Out[gcur * DIM + d], s);
            gcur = g;
            s = 0.f;
        }
        s += bflo((uint)H[(size_t)node * DIM + d]);
    }
    if (gcur >= 0) atomicAdd(&Out[gcur * DIM + d], s);
}

// ---------------- launch ----------------

extern "C" void kernel_launch(void* const* d_in, const int* in_sizes, int n_in,
                              void* d_out, int out_size, void* d_ws, size_t ws_size,
                              hipStream_t stream) {
    const float* x  = (const float*)d_in[0];
    const float* W1 = (const float*)d_in[1];
    const float* b1 = (const float*)d_in[2];
    const float* W2 = (const float*)d_in[3];
    const float* b2 = (const float*)d_in[4];
    const float* W3 = (const float*)d_in[5];
    const float* b3 = (const float*)d_in[6];
    const int*   ei = (const int*)d_in[7];
    const int*   bv = (const int*)d_in[8];
    float* out = (float*)d_out;

    const int N = N_NODES, E = N_EDGES;

    char* p = (char*)d_ws;
    auto alloc = [&](size_t bytes) -> void* {
        void* r = (void*)p;
        p += (bytes + 255) & ~(size_t)255;
        return r;
    };
    int*    bcnt_pad = (int*)alloc((size_t)NB * 16 * 4);
    int*    bcur_pad = (int*)alloc((size_t)NB * 16 * 4);
    int*    bbase    = (int*)alloc((size_t)(NB + 1) * 4);
    int*    row_ptr  = (int*)alloc((size_t)(N + 1) * 4);
    float*  dis      = (float*)alloc((size_t)N * 4);
    uint*   stage    = (uint*)alloc((size_t)E * 4);
    int*    col      = (int*)alloc((size_t)E * 4);
    ushort* B1       = (ushort*)alloc((size_t)N * DIM * 2);
    ushort* B2       = (ushort*)alloc((size_t)N * DIM * 2);

    const int* src = ei;
    const int* dst = ei + E;

    hipMemsetAsync(d_out, 0, (size_t)N_GRAPHS * DIM * sizeof(float), stream);
    hipMemsetAsync(bcnt_pad, 0, (size_t)NB * 16 * 4, stream);

    bhist_k<<<NCHUNK, 256, 0, stream>>>(dst, bcnt_pad, E);
    bscan_k<<<1, 64, 0, stream>>>(bcnt_pad, bbase, bcur_pad);
    bscat_k<<<NCHUNK, 256, 0, stream>>>(src, dst, bcur_pad, stage, E);
    csr_k<<<NB, 256, 0, stream>>>(stage, bbase, row_ptr, dis, col);

    int gemm_grid = (N + GEMM_ROWS - 1) / GEMM_ROWS;
    int agg_grid  = AGG_G * 8;

    gemm_k<float><<<gemm_grid, 256, 0, stream>>>(x,  W1, B1, N);
    agg_k<<<agg_grid, 256, 0, stream>>>(B1, row_ptr, col, dis, b1, B2);

    gemm_k<ushort><<<gemm_grid, 256, 0, stream>>>(B2, W2, B1, N);
    agg_k<<<agg_grid, 256, 0, stream>>>(B1, row_ptr, col, dis, b2, B2);

    gemm_k<ushort><<<gemm_grid, 256, 0, stream>>>(B2, W3, B1, N);
    agg_k<<<agg_grid, 256, 0, stream>>>(B1, row_ptr, col, dis, b3, B2);

    pool_k<<<(N + 63) / 64, 128, 0, stream>>>(B2, bv, out, N);
}

// Round 11
// 304.586 us; speedup vs baseline: 1.3274x; 1.3274x over previous
//
#include <hip/hip_runtime.h>

#define N_NODES 50000
#define N_EDGES 800000
#define N_GRAPHS 512
#define DIM 128
#define N_PAD 50048

#define BW_LOG 9
#define BWID 512                                  // nodes per bucket
#define NB ((N_NODES + BWID - 1) / BWID)          // 98
#define CHUNK 4096                                // edges per phase-A block
#define NCHUNK ((N_EDGES + CHUNK - 1) / CHUNK)    // 196

typedef unsigned int uint;
typedef unsigned short ushort;
typedef __attribute__((ext_vector_type(8))) short bf16x8;
typedef __attribute__((ext_vector_type(4))) float f32x4;

// bf16 helpers (RNE pack, cheap unpack)
__device__ __forceinline__ ushort f2bf(float f) {
    uint u = __float_as_uint(f);
    return (ushort)((u + 0x7fffu + ((u >> 16) & 1u)) >> 16);
}
__device__ __forceinline__ float bf2f(ushort h) { return __uint_as_float((uint)h << 16); }
__device__ __forceinline__ float bflo(uint p) { return __uint_as_float(p << 16); }
__device__ __forceinline__ float bfhi(uint p) { return __uint_as_float(p & 0xffff0000u); }

// ---------------- CSR build: bucket-sorted ----------------

__global__ __launch_bounds__(256) void bhist_k(const int* __restrict__ dst,
                                               int* __restrict__ bcnt_pad, int e) {
    __shared__ int h[NB];
    int t = threadIdx.x;
    for (int i = t; i < NB; i += 256) h[i] = 0;
    __syncthreads();
    int base = blockIdx.x * CHUNK;
    for (int i = t; i < CHUNK; i += 256) {
        int idx = base + i;
        if (idx < e) atomicAdd(&h[dst[idx] >> BW_LOG], 1);
    }
    __syncthreads();
    for (int i = t; i < NB; i += 256)
        if (h[i]) atomicAdd(&bcnt_pad[i << 4], h[i]);
}

__global__ void bscan_k(const int* __restrict__ bcnt_pad, int* __restrict__ bbase,
                        int* __restrict__ bcur_pad) {
    if (threadIdx.x == 0) {
        int run = 0;
        for (int b = 0; b < NB; b++) {
            bbase[b] = run;
            bcur_pad[b << 4] = run;
            run += bcnt_pad[b << 4];
        }
        bbase[NB] = run;
    }
}

// packed record: (src << 9) | (dst & 511)
__global__ __launch_bounds__(256) void bscat_k(const int* __restrict__ src,
                                               const int* __restrict__ dst,
                                               int* __restrict__ bcur_pad,
                                               uint* __restrict__ stage, int e) {
    __shared__ int h[NB];
    __shared__ int bb[NB];
    __shared__ int lc[NB];
    int t = threadIdx.x;
    for (int i = t; i < NB; i += 256) h[i] = 0;
    __syncthreads();
    int base = blockIdx.x * CHUNK;
    for (int i = t; i < CHUNK; i += 256) {
        int idx = base + i;
        if (idx < e) atomicAdd(&h[dst[idx] >> BW_LOG], 1);
    }
    __syncthreads();
    for (int i = t; i < NB; i += 256) {
        int c = h[i];
        bb[i] = c ? atomicAdd(&bcur_pad[i << 4], c) : 0;
        lc[i] = 0;
    }
    __syncthreads();
    for (int i = t; i < CHUNK; i += 256) {
        int idx = base + i;
        if (idx < e) {
            int d = dst[idx];
            int b = d >> BW_LOG;
            int r = atomicAdd(&lc[b], 1);
            stage[bb[b] + r] = ((uint)src[idx] << BW_LOG) | (uint)(d & (BWID - 1));
        }
    }
}

__global__ __launch_bounds__(256) void csr_k(const uint* __restrict__ stage,
                                             const int* __restrict__ bbase,
                                             int* __restrict__ row_ptr,
                                             float* __restrict__ dis,
                                             int* __restrict__ col) {
    __shared__ int hist[BWID];
    __shared__ int excl[BWID];
    __shared__ int ws[256];
    int b = blockIdx.x, t = threadIdx.x;
    int beg = bbase[b], end = bbase[b + 1];
    for (int i = t; i < BWID; i += 256) hist[i] = 0;
    __syncthreads();
    for (int i = beg + t; i < end; i += 256)
        atomicAdd(&hist[stage[i] & (BWID - 1)], 1);
    __syncthreads();
    int s = hist[2 * t] + hist[2 * t + 1];
    ws[t] = s;
    __syncthreads();
    for (int o = 1; o < 256; o <<= 1) {
        int v = ws[t];
        int add = (t >= o) ? ws[t - o] : 0;
        __syncthreads();
        ws[t] = v + add;
        __syncthreads();
    }
    int pre = (t == 0) ? 0 : ws[t - 1];
    excl[2 * t] = pre;
    excl[2 * t + 1] = pre + hist[2 * t];
    __syncthreads();
    int node0 = b * BWID;
    for (int i = t; i < BWID; i += 256) {
        int node = node0 + i;
        if (node < N_NODES) {
            row_ptr[node] = beg + excl[i];
            dis[node] = rsqrtf((float)(hist[i] + 1));   // +1 = self-loop
        } else if (node == N_NODES) {
            row_ptr[node] = beg + excl[i];
        }
    }
    __syncthreads();
    for (int i = t; i < BWID; i += 256) hist[i] = excl[i];
    __syncthreads();
    for (int i = beg + t; i < end; i += 256) {
        uint p = stage[i];
        int d9 = p & (BWID - 1);
        int r = atomicAdd(&hist[d9], 1);
        col[beg + r] = (int)(p >> BW_LOG);
    }
}

// ---------------- W conversion: split-precision, n-major ----------------
// Whi[n*128+k] = bf16(W[k][n]); Wlo[n*128+k] = bf16(W[k][n] - Whi)

__global__ void wconv_k(const float* __restrict__ W, ushort* __restrict__ Whi,
                        ushort* __restrict__ Wlo) {
    int i = blockIdx.x * 256 + threadIdx.x;   // 16384
    int k = i >> 7, nn = i & 127;
    float w = W[i];
    ushort h = f2bf(w);
    Whi[nn * 128 + k] = h;
    Wlo[nn * 128 + k] = f2bf(w - bf2f(h));
}

// ---------------- MFMA GEMM, split-precision W (and A for fp32 input) ----------------
// block: 256 thr = 4 waves, 64 rows. Wave w: rows w*16..w*16+15, full 128 cols.
// A-frag: m=lane&15, k=quad*8+j. B-frag from LDS W^T (n-major, +8 pad): n=lane&15.
// D: col=lane&15, row=quad*4+reg.
// acc = A_hi@W_hi (+ A_lo@W_hi if fp32 in) + A_hi@W_lo  -> ~fp32-accurate.

template <typename TIn>
__global__ __launch_bounds__(256) void gemm_mfma_k(const TIn* __restrict__ X,
                                                   const ushort* __restrict__ Whi,
                                                   const ushort* __restrict__ Wlo,
                                                   ushort* __restrict__ H, int n) {
    __shared__ __align__(16) ushort lds[128 * 136];   // 34 KB; re-staged per pass
    int t = threadIdx.x;

    auto stageW = [&](const ushort* Wsw) {
#pragma unroll
        for (int j = 0; j < 8; j++) {
            int idx8 = t + j * 256;              // 2048 octets
            int nn = idx8 >> 4;
            int k0 = (idx8 & 15) * 8;
            uint4 v = ((const uint4*)Wsw)[idx8];
            *(uint4*)&lds[nn * 136 + k0] = v;
        }
    };

    stageW(Whi);

    int w = t >> 6, l = t & 63;
    int quad = l >> 4, lr = l & 15;
    int arow = blockIdx.x * 64 + w * 16 + lr;
    int srow = arow < n ? arow : n - 1;          // clamp: no OOB read

    bf16x8 a[4], alo[4];
#pragma unroll
    for (int q = 0; q < 4; q++) {
        if constexpr (sizeof(TIn) == 4) {
            const float4* xp = (const float4*)(X + (size_t)srow * DIM + q * 32 + quad * 8);
            float4 v0 = xp[0], v1 = xp[1];
            float f[8] = {v0.x, v0.y, v0.z, v0.w, v1.x, v1.y, v1.z, v1.w};
            bf16x8 ah, al;
#pragma unroll
            for (int j = 0; j < 8; j++) {
                ushort h = f2bf(f[j]);
                ah[j] = (short)h;
                al[j] = (short)f2bf(f[j] - bf2f(h));
            }
            a[q] = ah;
            alo[q] = al;
        } else {
            a[q] = *(const bf16x8*)(X + (size_t)srow * DIM + q * 32 + quad * 8);
        }
    }

    f32x4 acc[8];
#pragma unroll
    for (int c = 0; c < 8; c++) acc[c] = (f32x4){0.f, 0.f, 0.f, 0.f};

    __syncthreads();
    // pass 1: A_hi @ W_hi (+ A_lo @ W_hi for fp32 input)
#pragma unroll
    for (int q = 0; q < 4; q++) {
#pragma unroll
        for (int c = 0; c < 8; c++) {
            bf16x8 b = *(const bf16x8*)&lds[(c * 16 + lr) * 136 + q * 32 + quad * 8];
            acc[c] = __builtin_amdgcn_mfma_f32_16x16x32_bf16(a[q], b, acc[c], 0, 0, 0);
            if constexpr (sizeof(TIn) == 4)
                acc[c] = __builtin_amdgcn_mfma_f32_16x16x32_bf16(alo[q], b, acc[c], 0, 0, 0);
        }
    }

    // pass 2: A_hi @ W_lo
    __syncthreads();
    stageW(Wlo);
    __syncthreads();
#pragma unroll
    for (int q = 0; q < 4; q++) {
#pragma unroll
        for (int c = 0; c < 8; c++) {
            bf16x8 b = *(const bf16x8*)&lds[(c * 16 + lr) * 136 + q * 32 + quad * 8];
            acc[c] = __builtin_amdgcn_mfma_f32_16x16x32_bf16(a[q], b, acc[c], 0, 0, 0);
        }
    }

    // epilogue: stage bf16 C tile in LDS, coalesced uint4 store
    __syncthreads();
#pragma unroll
    for (int c = 0; c < 8; c++) {
#pragma unroll
        for (int r = 0; r < 4; r++) {
            int rl = w * 16 + quad * 4 + r;
            lds[rl * 136 + c * 16 + lr] = f2bf(acc[c][r]);
        }
    }
    __syncthreads();
    // 64 rows x 16 uint4 slots (128 ushorts/row) = 1024 slots
    // (round 8-10 bug: only 512 slots -> cols 64..127 never stored)
#pragma unroll
    for (int j = 0; j < 4; j++) {
        int idx = t + j * 256;
        int rl = idx >> 4, sl = idx & 15;
        int grow = blockIdx.x * 64 + rl;
        if (grow < n) {
            uint4 v = *(const uint4*)&lds[rl * 136 + sl * 8];
            ((uint4*)(H + (size_t)grow * DIM))[sl] = v;
        }
    }
}

// ---------------- CSR aggregation (2 nodes/wave, 256B row gather) ----------------

__global__ __launch_bounds__(256) void agg_k(const ushort* __restrict__ H,
                                             const int* __restrict__ row_ptr,
                                             const int* __restrict__ col,
                                             const float* __restrict__ dis,
                                             const float* __restrict__ bias,
                                             ushort* __restrict__ Out, int n) {
    int node = blockIdx.x * 8 + (threadIdx.x >> 5);
    int lane = threadIdx.x & 31;        // 32 lanes per node, 4 features/lane
    if (node >= n) return;
    float dn = dis[node];
    int beg = row_ptr[node], end = row_ptr[node + 1];
    uint2 pw = *(const uint2*)(H + (size_t)node * DIM + lane * 4);  // self-loop row
    float a0 = dn * bflo(pw.x), a1 = dn * bfhi(pw.x);
    float a2 = dn * bflo(pw.y), a3 = dn * bfhi(pw.y);
    int e = beg;
    for (; e + 3 < end; e += 4) {
        int c0 = col[e], c1 = col[e + 1], c2 = col[e + 2], c3 = col[e + 3];
        float w0 = dis[c0], w1 = dis[c1], w2 = dis[c2], w3 = dis[c3];
        uint2 p0 = *(const uint2*)(H + (size_t)c0 * DIM + lane * 4);
        uint2 p1 = *(const uint2*)(H + (size_t)c1 * DIM + lane * 4);
        uint2 p2 = *(const uint2*)(H + (size_t)c2 * DIM + lane * 4);
        uint2 p3 = *(const uint2*)(H + (size_t)c3 * DIM + lane * 4);
        a0 += w0 * bflo(p0.x) + w1 * bflo(p1.x) + w2 * bflo(p2.x) + w3 * bflo(p3.x);
        a1 += w0 * bfhi(p0.x) + w1 * bfhi(p1.x) + w2 * bfhi(p2.x) + w3 * bfhi(p3.x);
        a2 += w0 * bflo(p0.y) + w1 * bflo(p1.y) + w2 * bflo(p2.y) + w3 * bflo(p3.y);
        a3 += w0 * bfhi(p0.y) + w1 * bfhi(p1.y) + w2 * bfhi(p2.y) + w3 * bfhi(p3.y);
    }
    for (; e < end; e++) {
        int c = col[e];
        float w = dis[c];
        uint2 p = *(const uint2*)(H + (size_t)c * DIM + lane * 4);
        a0 += w * bflo(p.x);
        a1 += w * bfhi(p.x);
        a2 += w * bflo(p.y);
        a3 += w * bfhi(p.y);
    }
    int d0 = lane * 4;
    a0 = fmaxf(a0 * dn + bias[d0], 0.f);
    a1 = fmaxf(a1 * dn + bias[d0 + 1], 0.f);
    a2 = fmaxf(a2 * dn + bias[d0 + 2], 0.f);
    a3 = fmaxf(a3 * dn + bias[d0 + 3], 0.f);
    uint o0 = (uint)f2bf(a0) | ((uint)f2bf(a1) << 16);
    uint o1 = (uint)f2bf(a2) | ((uint)f2bf(a3) << 16);
    *(uint2*)(Out + (size_t)node * DIM + d0) = make_uint2(o0, o1);
}

// ---------------- global add pool (batch_vec sorted, bf16 in, fp32 out) ----------------

__global__ void pool_k(const ushort* __restrict__ H, const int* __restrict__ batch,
                       float* Out, int n) {
    int d = threadIdx.x;
    int n0 = blockIdx.x * 64;
    int gcur = -1;
    float s = 0.f;
    for (int i = 0; i < 64; i++) {
        int node = n0 + i;
        if (node >= n) break;
        int g = batch[node];
        if (g != gcur) {
            if (gcur >= 0) atomicAdd(&Out[gcur * DIM + d], s);
            gcur = g;
            s = 0.f;
        }
        s += bflo((uint)H[(size_t)node * DIM + d]);
    }
    if (gcur >= 0) atomicAdd(&Out[gcur * DIM + d], s);
}

// ---------------- launch ----------------

extern "C" void kernel_launch(void* const* d_in, const int* in_sizes, int n_in,
                              void* d_out, int out_size, void* d_ws, size_t ws_size,
                              hipStream_t stream) {
    const float* x  = (const float*)d_in[0];
    const float* W1 = (const float*)d_in[1];
    const float* b1 = (const float*)d_in[2];
    const float* W2 = (const float*)d_in[3];
    const float* b2 = (const float*)d_in[4];
    const float* W3 = (const float*)d_in[5];
    const float* b3 = (const float*)d_in[6];
    const int*   ei = (const int*)d_in[7];
    const int*   bv = (const int*)d_in[8];
    float* out = (float*)d_out;

    const int N = N_NODES, E = N_EDGES;

    char* p = (char*)d_ws;
    auto alloc = [&](size_t bytes) -> void* {
        void* r = (void*)p;
        p += (bytes + 255) & ~(size_t)255;
        return r;
    };
    int*    bcnt_pad = (int*)alloc((size_t)NB * 16 * 4);
    int*    bcur_pad = (int*)alloc((size_t)NB * 16 * 4);
    int*    bbase    = (int*)alloc((size_t)(NB + 1) * 4);
    int*    row_ptr  = (int*)alloc((size_t)(N + 1) * 4);
    float*  dis      = (float*)alloc((size_t)N * 4);
    uint*   stage    = (uint*)alloc((size_t)E * 4);
    int*    col      = (int*)alloc((size_t)E * 4);
    ushort* B1       = (ushort*)alloc((size_t)N_PAD * DIM * 2);
    ushort* B2       = (ushort*)alloc((size_t)N_PAD * DIM * 2);

    // W buffers overlaid on stage (dead after csr_k; wconv runs after it in-stream)
    ushort* Whi1 = (ushort*)stage;
    ushort* Wlo1 = Whi1 + (size_t)DIM * DIM;
    ushort* Whi2 = Wlo1 + (size_t)DIM * DIM;
    ushort* Wlo2 = Whi2 + (size_t)DIM * DIM;
    ushort* Whi3 = Wlo2 + (size_t)DIM * DIM;
    ushort* Wlo3 = Whi3 + (size_t)DIM * DIM;

    const int* src = ei;
    const int* dst = ei + E;

    hipMemsetAsync(d_out, 0, (size_t)N_GRAPHS * DIM * sizeof(float), stream);
    hipMemsetAsync(bcnt_pad, 0, (size_t)NB * 16 * 4, stream);

    bhist_k<<<NCHUNK, 256, 0, stream>>>(dst, bcnt_pad, E);
    bscan_k<<<1, 64, 0, stream>>>(bcnt_pad, bbase, bcur_pad);
    bscat_k<<<NCHUNK, 256, 0, stream>>>(src, dst, bcur_pad, stage, E);
    csr_k<<<NB, 256, 0, stream>>>(stage, bbase, row_ptr, dis, col);

    wconv_k<<<64, 256, 0, stream>>>(W1, Whi1, Wlo1);
    wconv_k<<<64, 256, 0, stream>>>(W2, Whi2, Wlo2);
    wconv_k<<<64, 256, 0, stream>>>(W3, Whi3, Wlo3);

    int gemm_grid = N_PAD / 64;          // 782
    int agg_grid  = (N + 7) / 8;

    gemm_mfma_k<float><<<gemm_grid, 256, 0, stream>>>(x, Whi1, Wlo1, B1, N);
    agg_k<<<agg_grid, 256, 0, stream>>>(B1, row_ptr, col, dis, b1, B2, N);

    gemm_mfma_k<ushort><<<gemm_grid, 256, 0, stream>>>(B2, Whi2, Wlo2, B1, N);
    agg_k<<<agg_grid, 256, 0, stream>>>(B1, row_ptr, col, dis, b2, B2, N);

    gemm_mfma_k<ushort><<<gemm_grid, 256, 0, stream>>>(B2, Whi3, Wlo3, B1, N);
    agg_k<<<agg_grid, 256, 0, stream>>>(B1, row_ptr, col, dis, b3, B2, N);

    pool_k<<<(N + 63) / 64, 128, 0, stream>>>(B2, bv, out, N);
}

// Round 12
// 290.759 us; speedup vs baseline: 1.3905x; 1.0476x over previous
//
#include <hip/hip_runtime.h>

#define N_NODES 50000
#define N_EDGES 800000
#define N_GRAPHS 512
#define DIM 128
#define N_PAD 50048

#define BW_LOG 9
#define BWID 512                                  // nodes per bucket
#define NB ((N_NODES + BWID - 1) / BWID)          // 98
#define CHUNK 4096                                // edges per phase-A block
#define NCHUNK ((N_EDGES + CHUNK - 1) / CHUNK)    // 196

typedef unsigned int uint;
typedef unsigned short ushort;
typedef __attribute__((ext_vector_type(8))) short bf16x8;
typedef __attribute__((ext_vector_type(4))) float f32x4;

// bf16 helpers (RNE pack, cheap unpack)
__device__ __forceinline__ ushort f2bf(float f) {
    uint u = __float_as_uint(f);
    return (ushort)((u + 0x7fffu + ((u >> 16) & 1u)) >> 16);
}
__device__ __forceinline__ float bf2f(ushort h) { return __uint_as_float((uint)h << 16); }
__device__ __forceinline__ float bflo(uint p) { return __uint_as_float(p << 16); }
__device__ __forceinline__ float bfhi(uint p) { return __uint_as_float(p & 0xffff0000u); }

// ---------------- CSR build: bucket-sorted ----------------

__global__ __launch_bounds__(256) void bhist_k(const int* __restrict__ dst,
                                               int* __restrict__ bcnt_pad, int e) {
    __shared__ int h[NB];
    int t = threadIdx.x;
    for (int i = t; i < NB; i += 256) h[i] = 0;
    __syncthreads();
    int base = blockIdx.x * CHUNK;
    for (int i = t; i < CHUNK; i += 256) {
        int idx = base + i;
        if (idx < e) atomicAdd(&h[dst[idx] >> BW_LOG], 1);
    }
    __syncthreads();
    for (int i = t; i < NB; i += 256)
        if (h[i]) atomicAdd(&bcnt_pad[i << 4], h[i]);
}

__global__ void bscan_k(const int* __restrict__ bcnt_pad, int* __restrict__ bbase,
                        int* __restrict__ bcur_pad) {
    if (threadIdx.x == 0) {
        int run = 0;
        for (int b = 0; b < NB; b++) {
            bbase[b] = run;
            bcur_pad[b << 4] = run;
            run += bcnt_pad[b << 4];
        }
        bbase[NB] = run;
    }
}

// packed record: (src << 9) | (dst & 511)
__global__ __launch_bounds__(256) void bscat_k(const int* __restrict__ src,
                                               const int* __restrict__ dst,
                                               int* __restrict__ bcur_pad,
                                               uint* __restrict__ stage, int e) {
    __shared__ int h[NB];
    __shared__ int bb[NB];
    __shared__ int lc[NB];
    int t = threadIdx.x;
    for (int i = t; i < NB; i += 256) h[i] = 0;
    __syncthreads();
    int base = blockIdx.x * CHUNK;
    for (int i = t; i < CHUNK; i += 256) {
        int idx = base + i;
        if (idx < e) atomicAdd(&h[dst[idx] >> BW_LOG], 1);
    }
    __syncthreads();
    for (int i = t; i < NB; i += 256) {
        int c = h[i];
        bb[i] = c ? atomicAdd(&bcur_pad[i << 4], c) : 0;
        lc[i] = 0;
    }
    __syncthreads();
    for (int i = t; i < CHUNK; i += 256) {
        int idx = base + i;
        if (idx < e) {
            int d = dst[idx];
            int b = d >> BW_LOG;
            int r = atomicAdd(&lc[b], 1);
            stage[bb[b] + r] = ((uint)src[idx] << BW_LOG) | (uint)(d & (BWID - 1));
        }
    }
}

__global__ __launch_bounds__(256) void csr_k(const uint* __restrict__ stage,
                                             const int* __restrict__ bbase,
                                             int* __restrict__ row_ptr,
                                             float* __restrict__ dis,
                                             int* __restrict__ col) {
    __shared__ int hist[BWID];
    __shared__ int excl[BWID];
    __shared__ int ws[256];
    int b = blockIdx.x, t = threadIdx.x;
    int beg = bbase[b], end = bbase[b + 1];
    for (int i = t; i < BWID; i += 256) hist[i] = 0;
    __syncthreads();
    for (int i = beg + t; i < end; i += 256)
        atomicAdd(&hist[stage[i] & (BWID - 1)], 1);
    __syncthreads();
    int s = hist[2 * t] + hist[2 * t + 1];
    ws[t] = s;
    __syncthreads();
    for (int o = 1; o < 256; o <<= 1) {
        int v = ws[t];
        int add = (t >= o) ? ws[t - o] : 0;
        __syncthreads();
        ws[t] = v + add;
        __syncthreads();
    }
    int pre = (t == 0) ? 0 : ws[t - 1];
    excl[2 * t] = pre;
    excl[2 * t + 1] = pre + hist[2 * t];
    __syncthreads();
    int node0 = b * BWID;
    for (int i = t; i < BWID; i += 256) {
        int node = node0 + i;
        if (node < N_NODES) {
            row_ptr[node] = beg + excl[i];
            dis[node] = rsqrtf((float)(hist[i] + 1));   // +1 = self-loop
        } else if (node == N_NODES) {
            row_ptr[node] = beg + excl[i];
        }
    }
    __syncthreads();
    for (int i = t; i < BWID; i += 256) hist[i] = excl[i];
    __syncthreads();
    for (int i = beg + t; i < end; i += 256) {
        uint p = stage[i];
        int d9 = p & (BWID - 1);
        int r = atomicAdd(&hist[d9], 1);
        col[beg + r] = (int)(p >> BW_LOG);
    }
}

// ---------------- W conversion: split-precision, n-major, all 3 layers in 1 dispatch ----

__global__ void wconv_k(const float* __restrict__ Wa, const float* __restrict__ Wb,
                        const float* __restrict__ Wc, ushort* __restrict__ Whi,
                        ushort* __restrict__ Wlo) {
    int i = blockIdx.x * 256 + threadIdx.x;   // 3*16384
    int layer = i >> 14, r = i & 16383;
    const float* W = layer == 0 ? Wa : (layer == 1 ? Wb : Wc);
    int k = r >> 7, nn = r & 127;
    float w = W[r];
    ushort h = f2bf(w);
    size_t o = (size_t)layer * DIM * DIM + nn * 128 + k;
    Whi[o] = h;
    Wlo[o] = f2bf(w - bf2f(h));
}

// ---------------- MFMA GEMM, split-precision W (and A for fp32 input) ----------------
// block: 256 thr = 4 waves, 64 rows. Wave w: rows w*16..w*16+15, full 128 cols.
// A-frag: m=lane&15, k=quad*8+j. B-frag from LDS W^T (n-major, +8 pad): n=lane&15.
// D: col=lane&15, row=quad*4+reg.
// acc = A_hi@W_hi (+ A_lo@W_hi if fp32 in) + A_hi@W_lo  -> ~fp32-accurate.

template <typename TIn>
__global__ __launch_bounds__(256) void gemm_mfma_k(const TIn* __restrict__ X,
                                                   const ushort* __restrict__ Whi,
                                                   const ushort* __restrict__ Wlo,
                                                   ushort* __restrict__ H, int n) {
    __shared__ __align__(16) ushort lds[128 * 136];   // 34 KB; re-staged per pass
    int t = threadIdx.x;

    auto stageW = [&](const ushort* Wsw) {
#pragma unroll
        for (int j = 0; j < 8; j++) {
            int idx8 = t + j * 256;              // 2048 octets
            int nn = idx8 >> 4;
            int k0 = (idx8 & 15) * 8;
            uint4 v = ((const uint4*)Wsw)[idx8];
            *(uint4*)&lds[nn * 136 + k0] = v;
        }
    };

    stageW(Whi);

    int w = t >> 6, l = t & 63;
    int quad = l >> 4, lr = l & 15;
    int arow = blockIdx.x * 64 + w * 16 + lr;
    int srow = arow < n ? arow : n - 1;          // clamp: no OOB read

    bf16x8 a[4], alo[4];
#pragma unroll
    for (int q = 0; q < 4; q++) {
        if constexpr (sizeof(TIn) == 4) {
            const float4* xp = (const float4*)(X + (size_t)srow * DIM + q * 32 + quad * 8);
            float4 v0 = xp[0], v1 = xp[1];
            float f[8] = {v0.x, v0.y, v0.z, v0.w, v1.x, v1.y, v1.z, v1.w};
            bf16x8 ah, al;
#pragma unroll
            for (int j = 0; j < 8; j++) {
                ushort h = f2bf(f[j]);
                ah[j] = (short)h;
                al[j] = (short)f2bf(f[j] - bf2f(h));
            }
            a[q] = ah;
            alo[q] = al;
        } else {
            a[q] = *(const bf16x8*)(X + (size_t)srow * DIM + q * 32 + quad * 8);
        }
    }

    f32x4 acc[8];
#pragma unroll
    for (int c = 0; c < 8; c++) acc[c] = (f32x4){0.f, 0.f, 0.f, 0.f};

    __syncthreads();
    // pass 1: A_hi @ W_hi (+ A_lo @ W_hi for fp32 input)
#pragma unroll
    for (int q = 0; q < 4; q++) {
#pragma unroll
        for (int c = 0; c < 8; c++) {
            bf16x8 b = *(const bf16x8*)&lds[(c * 16 + lr) * 136 + q * 32 + quad * 8];
            acc[c] = __builtin_amdgcn_mfma_f32_16x16x32_bf16(a[q], b, acc[c], 0, 0, 0);
            if constexpr (sizeof(TIn) == 4)
                acc[c] = __builtin_amdgcn_mfma_f32_16x16x32_bf16(alo[q], b, acc[c], 0, 0, 0);
        }
    }

    // pass 2: A_hi @ W_lo
    __syncthreads();
    stageW(Wlo);
    __syncthreads();
#pragma unroll
    for (int q = 0; q < 4; q++) {
#pragma unroll
        for (int c = 0; c < 8; c++) {
            bf16x8 b = *(const bf16x8*)&lds[(c * 16 + lr) * 136 + q * 32 + quad * 8];
            acc[c] = __builtin_amdgcn_mfma_f32_16x16x32_bf16(a[q], b, acc[c], 0, 0, 0);
        }
    }

    // epilogue: stage bf16 C tile in LDS, coalesced uint4 store (ALL 16 slots/row)
    __syncthreads();
#pragma unroll
    for (int c = 0; c < 8; c++) {
#pragma unroll
        for (int r = 0; r < 4; r++) {
            int rl = w * 16 + quad * 4 + r;
            lds[rl * 136 + c * 16 + lr] = f2bf(acc[c][r]);
        }
    }
    __syncthreads();
#pragma unroll
    for (int j = 0; j < 4; j++) {
        int idx = t + j * 256;                   // 1024 slots = 64 rows x 16 uint4
        int rl = idx >> 4, sl = idx & 15;
        int grow = blockIdx.x * 64 + rl;
        if (grow < n) {
            uint4 v = *(const uint4*)&lds[rl * 136 + sl * 8];
            ((uint4*)(H + (size_t)grow * DIM))[sl] = v;
        }
    }
}

// ---------------- CSR aggregation: 16 lanes/node, uint4 gathers, 4-edge unroll --------
// one edge = one uint4 load instr per 16-lane group (256B row); 4 groups/wave x 4
// unrolled = 16 outstanding 256B gathers per wave (2x the 32-lane variant).
// Self-loop analytic: acc init = dn*h[node]; final scale by dn.

__global__ __launch_bounds__(256) void agg_k(const ushort* __restrict__ H,
                                             const int* __restrict__ row_ptr,
                                             const int* __restrict__ col,
                                             const float* __restrict__ dis,
                                             const float* __restrict__ bias,
                                             ushort* __restrict__ Out, int n) {
    int node = blockIdx.x * 16 + (threadIdx.x >> 4);
    int lane = threadIdx.x & 15;        // 16 lanes per node, 8 features/lane
    if (node >= n) return;
    const ushort* Hl = H + lane * 8;
    float dn = dis[node];
    int beg = row_ptr[node], end = row_ptr[node + 1];

    uint4 pw = *(const uint4*)(Hl + (size_t)node * DIM);   // self-loop row
    float a0 = dn * bflo(pw.x), a1 = dn * bfhi(pw.x);
    float a2 = dn * bflo(pw.y), a3 = dn * bfhi(pw.y);
    float a4 = dn * bflo(pw.z), a5 = dn * bfhi(pw.z);
    float a6 = dn * bflo(pw.w), a7 = dn * bfhi(pw.w);

    int e = beg;
    for (; e + 3 < end; e += 4) {
        int c0 = col[e], c1 = col[e + 1], c2 = col[e + 2], c3 = col[e + 3];
        float w0 = dis[c0], w1 = dis[c1], w2 = dis[c2], w3 = dis[c3];
        uint4 p0 = *(const uint4*)(Hl + (size_t)c0 * DIM);
        uint4 p1 = *(const uint4*)(Hl + (size_t)c1 * DIM);
        uint4 p2 = *(const uint4*)(Hl + (size_t)c2 * DIM);
        uint4 p3 = *(const uint4*)(Hl + (size_t)c3 * DIM);
        a0 += w0 * bflo(p0.x) + w1 * bflo(p1.x) + w2 * bflo(p2.x) + w3 * bflo(p3.x);
        a1 += w0 * bfhi(p0.x) + w1 * bfhi(p1.x) + w2 * bfhi(p2.x) + w3 * bfhi(p3.x);
        a2 += w0 * bflo(p0.y) + w1 * bflo(p1.y) + w2 * bflo(p2.y) + w3 * bflo(p3.y);
        a3 += w0 * bfhi(p0.y) + w1 * bfhi(p1.y) + w2 * bfhi(p2.y) + w3 * bfhi(p3.y);
        a4 += w0 * bflo(p0.z) + w1 * bflo(p1.z) + w2 * bflo(p2.z) + w3 * bflo(p3.z);
        a5 += w0 * bfhi(p0.z) + w1 * bfhi(p1.z) + w2 * bfhi(p2.z) + w3 * bfhi(p3.z);
        a6 += w0 * bflo(p0.w) + w1 * bflo(p1.w) + w2 * bflo(p2.w) + w3 * bflo(p3.w);
        a7 += w0 * bfhi(p0.w) + w1 * bfhi(p1.w) + w2 * bfhi(p2.w) + w3 * bfhi(p3.w);
    }
    for (; e < end; e++) {
        int c = col[e];
        float w = dis[c];
        uint4 p = *(const uint4*)(Hl + (size_t)c * DIM);
        a0 += w * bflo(p.x);
        a1 += w * bfhi(p.x);
        a2 += w * bflo(p.y);
        a3 += w * bfhi(p.y);
        a4 += w * bflo(p.z);
        a5 += w * bfhi(p.z);
        a6 += w * bflo(p.w);
        a7 += w * bfhi(p.w);
    }
    int d0 = lane * 8;
    a0 = fmaxf(a0 * dn + bias[d0], 0.f);
    a1 = fmaxf(a1 * dn + bias[d0 + 1], 0.f);
    a2 = fmaxf(a2 * dn + bias[d0 + 2], 0.f);
    a3 = fmaxf(a3 * dn + bias[d0 + 3], 0.f);
    a4 = fmaxf(a4 * dn + bias[d0 + 4], 0.f);
    a5 = fmaxf(a5 * dn + bias[d0 + 5], 0.f);
    a6 = fmaxf(a6 * dn + bias[d0 + 6], 0.f);
    a7 = fmaxf(a7 * dn + bias[d0 + 7], 0.f);
    uint4 o;
    o.x = (uint)f2bf(a0) | ((uint)f2bf(a1) << 16);
    o.y = (uint)f2bf(a2) | ((uint)f2bf(a3) << 16);
    o.z = (uint)f2bf(a4) | ((uint)f2bf(a5) << 16);
    o.w = (uint)f2bf(a6) | ((uint)f2bf(a7) << 16);
    *(uint4*)(Out + (size_t)node * DIM + d0) = o;
}

// ---------------- global add pool (batch_vec sorted, bf16 in, fp32 out) ----------------

__global__ void pool_k(const ushort* __restrict__ H, const int* __restrict__ batch,
                       float* Out, int n) {
    int d = threadIdx.x;
    int n0 = blockIdx.x * 64;
    int gcur = -1;
    float s = 0.f;
    for (int i = 0; i < 64; i++) {
        int node = n0 + i;
        if (node >= n) break;
        int g = batch[node];
        if (g != gcur) {
            if (gcur >= 0) atomicAdd(&Out[gcur * DIM + d], s);
            gcur = g;
            s = 0.f;
        }
        s += bflo((uint)H[(size_t)node * DIM + d]);
    }
    if (gcur >= 0) atomicAdd(&Out[gcur * DIM + d], s);
}

// ---------------- launch ----------------

extern "C" void kernel_launch(void* const* d_in, const int* in_sizes, int n_in,
                              void* d_out, int out_size, void* d_ws, size_t ws_size,
                              hipStream_t stream) {
    const float* x  = (const float*)d_in[0];
    const float* W1 = (const float*)d_in[1];
    const float* b1 = (const float*)d_in[2];
    const float* W2 = (const float*)d_in[3];
    const float* b2 = (const float*)d_in[4];
    const float* W3 = (const float*)d_in[5];
    const float* b3 = (const float*)d_in[6];
    const int*   ei = (const int*)d_in[7];
    const int*   bv = (const int*)d_in[8];
    float* out = (float*)d_out;

    const int N = N_NODES, E = N_EDGES;

    char* p = (char*)d_ws;
    auto alloc = [&](size_t bytes) -> void* {
        void* r = (void*)p;
        p += (bytes + 255) & ~(size_t)255;
        return r;
    };
    int*    bcnt_pad = (int*)alloc((size_t)NB * 16 * 4);
    int*    bcur_pad = (int*)alloc((size_t)NB * 16 * 4);
    int*    bbase    = (int*)alloc((size_t)(NB + 1) * 4);
    int*    row_ptr  = (int*)alloc((size_t)(N + 1) * 4);
    float*  dis      = (float*)alloc((size_t)N * 4);
    uint*   stage    = (uint*)alloc((size_t)E * 4);
    int*    col      = (int*)alloc((size_t)E * 4);
    ushort* B1       = (ushort*)alloc((size_t)N_PAD * DIM * 2);
    ushort* B2       = (ushort*)alloc((size_t)N_PAD * DIM * 2);

    // W buffers overlaid on stage (dead after csr_k; wconv runs after it in-stream)
    ushort* Whi = (ushort*)stage;                        // 3 * 16384
    ushort* Wlo = Whi + (size_t)3 * DIM * DIM;

    const int* src = ei;
    const int* dst = ei + E;

    hipMemsetAsync(d_out, 0, (size_t)N_GRAPHS * DIM * sizeof(float), stream);
    hipMemsetAsync(bcnt_pad, 0, (size_t)NB * 16 * 4, stream);

    bhist_k<<<NCHUNK, 256, 0, stream>>>(dst, bcnt_pad, E);
    bscan_k<<<1, 64, 0, stream>>>(bcnt_pad, bbase, bcur_pad);
    bscat_k<<<NCHUNK, 256, 0, stream>>>(src, dst, bcur_pad, stage, E);
    csr_k<<<NB, 256, 0, stream>>>(stage, bbase, row_ptr, dis, col);

    wconv_k<<<192, 256, 0, stream>>>(W1, W2, W3, Whi, Wlo);

    int gemm_grid = N_PAD / 64;          // 782
    int agg_grid  = (N + 15) / 16;

    gemm_mfma_k<float><<<gemm_grid, 256, 0, stream>>>(x, Whi, Wlo, B1, N);
    agg_k<<<agg_grid, 256, 0, stream>>>(B1, row_ptr, col, dis, b1, B2, N);

    gemm_mfma_k<ushort><<<gemm_grid, 256, 0, stream>>>(B2, Whi + (size_t)DIM * DIM,
                                                       Wlo + (size_t)DIM * DIM, B1, N);
    agg_k<<<agg_grid, 256, 0, stream>>>(B1, row_ptr, col, dis, b2, B2, N);

    gemm_mfma_k<ushort><<<gemm_grid, 256, 0, stream>>>(B2, Whi + (size_t)2 * DIM * DIM,
                                                       Wlo + (size_t)2 * DIM * DIM, B1, N);
    agg_k<<<agg_grid, 256, 0, stream>>>(B1, row_ptr, col, dis, b3, B2, N);

    pool_k<<<(N + 63) / 64, 128, 0, stream>>>(B2, bv, out, N);
}

// Round 13
// 288.721 us; speedup vs baseline: 1.4003x; 1.0071x over previous
//
#include <hip/hip_runtime.h>

#define N_NODES 50000
#define N_EDGES 800000
#define N_GRAPHS 512
#define DIM 128
#define N_PAD 50048

#define BW_LOG 9
#define BWID 512                                  // nodes per bucket
#define NB ((N_NODES + BWID - 1) / BWID)          // 98
#define CHUNK 4096                                // edges per phase-A block
#define NCHUNK ((N_EDGES + CHUNK - 1) / CHUNK)    // 196

typedef unsigned int uint;
typedef unsigned short ushort;
typedef __attribute__((ext_vector_type(8))) short bf16x8;
typedef __attribute__((ext_vector_type(4))) float f32x4;

// bf16 helpers (RNE pack, cheap unpack)
__device__ __forceinline__ ushort f2bf(float f) {
    uint u = __float_as_uint(f);
    return (ushort)((u + 0x7fffu + ((u >> 16) & 1u)) >> 16);
}
__device__ __forceinline__ float bf2f(ushort h) { return __uint_as_float((uint)h << 16); }
__device__ __forceinline__ float bflo(uint p) { return __uint_as_float(p << 16); }
__device__ __forceinline__ float bfhi(uint p) { return __uint_as_float(p & 0xffff0000u); }

// ---------------- CSR build: bucket-sorted ----------------

__global__ __launch_bounds__(256) void bhist_k(const int* __restrict__ dst,
                                               int* __restrict__ bcnt_pad, int e) {
    __shared__ int h[NB];
    int t = threadIdx.x;
    for (int i = t; i < NB; i += 256) h[i] = 0;
    __syncthreads();
    int base = blockIdx.x * CHUNK;
    for (int i = t; i < CHUNK; i += 256) {
        int idx = base + i;
        if (idx < e) atomicAdd(&h[dst[idx] >> BW_LOG], 1);
    }
    __syncthreads();
    for (int i = t; i < NB; i += 256)
        if (h[i]) atomicAdd(&bcnt_pad[i << 4], h[i]);
}

// parallel 98-wide exclusive scan (one 128-thread block)
__global__ void bscan_k(const int* __restrict__ bcnt_pad, int* __restrict__ bbase,
                        int* __restrict__ bcur_pad) {
    __shared__ int v[128];
    int t = threadIdx.x;
    int x = (t < NB) ? bcnt_pad[t << 4] : 0;
    v[t] = x;
    __syncthreads();
    for (int o = 1; o < 128; o <<= 1) {
        int val = v[t];
        int add = (t >= o) ? v[t - o] : 0;
        __syncthreads();
        v[t] = val + add;
        __syncthreads();
    }
    if (t < NB) {
        int excl = (t == 0) ? 0 : v[t - 1];
        bbase[t] = excl;
        bcur_pad[t << 4] = excl;
    }
    if (t == NB - 1) bbase[NB] = v[t];
}

// packed record: (src << 9) | (dst & 511)
__global__ __launch_bounds__(256) void bscat_k(const int* __restrict__ src,
                                               const int* __restrict__ dst,
                                               int* __restrict__ bcur_pad,
                                               uint* __restrict__ stage, int e) {
    __shared__ int h[NB];
    __shared__ int bb[NB];
    __shared__ int lc[NB];
    int t = threadIdx.x;
    for (int i = t; i < NB; i += 256) h[i] = 0;
    __syncthreads();
    int base = blockIdx.x * CHUNK;
    for (int i = t; i < CHUNK; i += 256) {
        int idx = base + i;
        if (idx < e) atomicAdd(&h[dst[idx] >> BW_LOG], 1);
    }
    __syncthreads();
    for (int i = t; i < NB; i += 256) {
        int c = h[i];
        bb[i] = c ? atomicAdd(&bcur_pad[i << 4], c) : 0;
        lc[i] = 0;
    }
    __syncthreads();
    for (int i = t; i < CHUNK; i += 256) {
        int idx = base + i;
        if (idx < e) {
            int d = dst[idx];
            int b = d >> BW_LOG;
            int r = atomicAdd(&lc[b], 1);
            stage[bb[b] + r] = ((uint)src[idx] << BW_LOG) | (uint)(d & (BWID - 1));
        }
    }
}

__global__ __launch_bounds__(256) void csr_k(const uint* __restrict__ stage,
                                             const int* __restrict__ bbase,
                                             int* __restrict__ row_ptr,
                                             float* __restrict__ dis,
                                             int* __restrict__ col) {
    __shared__ int hist[BWID];
    __shared__ int excl[BWID];
    __shared__ int ws[256];
    int b = blockIdx.x, t = threadIdx.x;
    int beg = bbase[b], end = bbase[b + 1];
    for (int i = t; i < BWID; i += 256) hist[i] = 0;
    __syncthreads();
    for (int i = beg + t; i < end; i += 256)
        atomicAdd(&hist[stage[i] & (BWID - 1)], 1);
    __syncthreads();
    int s = hist[2 * t] + hist[2 * t + 1];
    ws[t] = s;
    __syncthreads();
    for (int o = 1; o < 256; o <<= 1) {
        int v = ws[t];
        int add = (t >= o) ? ws[t - o] : 0;
        __syncthreads();
        ws[t] = v + add;
        __syncthreads();
    }
    int pre = (t == 0) ? 0 : ws[t - 1];
    excl[2 * t] = pre;
    excl[2 * t + 1] = pre + hist[2 * t];
    __syncthreads();
    int node0 = b * BWID;
    for (int i = t; i < BWID; i += 256) {
        int node = node0 + i;
        if (node < N_NODES) {
            row_ptr[node] = beg + excl[i];
            dis[node] = rsqrtf((float)(hist[i] + 1));   // +1 = self-loop
        } else if (node == N_NODES) {
            row_ptr[node] = beg + excl[i];
        }
    }
    __syncthreads();
    for (int i = t; i < BWID; i += 256) hist[i] = excl[i];
    __syncthreads();
    for (int i = beg + t; i < end; i += 256) {
        uint p = stage[i];
        int d9 = p & (BWID - 1);
        int r = atomicAdd(&hist[d9], 1);
        col[beg + r] = (int)(p >> BW_LOG);
    }
}

// ---------------- W conversion: split-precision, n-major, all 3 layers ----------------

__global__ void wconv_k(const float* __restrict__ Wa, const float* __restrict__ Wb,
                        const float* __restrict__ Wc, ushort* __restrict__ Whi,
                        ushort* __restrict__ Wlo) {
    int i = blockIdx.x * 256 + threadIdx.x;   // 3*16384
    int layer = i >> 14, r = i & 16383;
    const float* W = layer == 0 ? Wa : (layer == 1 ? Wb : Wc);
    int k = r >> 7, nn = r & 127;
    float w = W[r];
    ushort h = f2bf(w);
    size_t o = (size_t)layer * DIM * DIM + nn * 128 + k;
    Whi[o] = h;
    Wlo[o] = f2bf(w - bf2f(h));
}

// ---------------- MFMA GEMM, split-precision W (and A for fp32 input) ----------------

template <typename TIn>
__global__ __launch_bounds__(256) void gemm_mfma_k(const TIn* __restrict__ X,
                                                   const ushort* __restrict__ Whi,
                                                   const ushort* __restrict__ Wlo,
                                                   ushort* __restrict__ H, int n) {
    __shared__ __align__(16) ushort lds[128 * 136];   // 34 KB; re-staged per pass
    int t = threadIdx.x;

    auto stageW = [&](const ushort* Wsw) {
#pragma unroll
        for (int j = 0; j < 8; j++) {
            int idx8 = t + j * 256;              // 2048 octets
            int nn = idx8 >> 4;
            int k0 = (idx8 & 15) * 8;
            uint4 v = ((const uint4*)Wsw)[idx8];
            *(uint4*)&lds[nn * 136 + k0] = v;
        }
    };

    stageW(Whi);

    int w = t >> 6, l = t & 63;
    int quad = l >> 4, lr = l & 15;
    int arow = blockIdx.x * 64 + w * 16 + lr;
    int srow = arow < n ? arow : n - 1;          // clamp: no OOB read

    bf16x8 a[4], alo[4];
#pragma unroll
    for (int q = 0; q < 4; q++) {
        if constexpr (sizeof(TIn) == 4) {
            const float4* xp = (const float4*)(X + (size_t)srow * DIM + q * 32 + quad * 8);
            float4 v0 = xp[0], v1 = xp[1];
            float f[8] = {v0.x, v0.y, v0.z, v0.w, v1.x, v1.y, v1.z, v1.w};
            bf16x8 ah, al;
#pragma unroll
            for (int j = 0; j < 8; j++) {
                ushort h = f2bf(f[j]);
                ah[j] = (short)h;
                al[j] = (short)f2bf(f[j] - bf2f(h));
            }
            a[q] = ah;
            alo[q] = al;
        } else {
            a[q] = *(const bf16x8*)(X + (size_t)srow * DIM + q * 32 + quad * 8);
        }
    }

    f32x4 acc[8];
#pragma unroll
    for (int c = 0; c < 8; c++) acc[c] = (f32x4){0.f, 0.f, 0.f, 0.f};

    __syncthreads();
#pragma unroll
    for (int q = 0; q < 4; q++) {
#pragma unroll
        for (int c = 0; c < 8; c++) {
            bf16x8 b = *(const bf16x8*)&lds[(c * 16 + lr) * 136 + q * 32 + quad * 8];
            acc[c] = __builtin_amdgcn_mfma_f32_16x16x32_bf16(a[q], b, acc[c], 0, 0, 0);
            if constexpr (sizeof(TIn) == 4)
                acc[c] = __builtin_amdgcn_mfma_f32_16x16x32_bf16(alo[q], b, acc[c], 0, 0, 0);
        }
    }

    __syncthreads();
    stageW(Wlo);
    __syncthreads();
#pragma unroll
    for (int q = 0; q < 4; q++) {
#pragma unroll
        for (int c = 0; c < 8; c++) {
            bf16x8 b = *(const bf16x8*)&lds[(c * 16 + lr) * 136 + q * 32 + quad * 8];
            acc[c] = __builtin_amdgcn_mfma_f32_16x16x32_bf16(a[q], b, acc[c], 0, 0, 0);
        }
    }

    __syncthreads();
#pragma unroll
    for (int c = 0; c < 8; c++) {
#pragma unroll
        for (int r = 0; r < 4; r++) {
            int rl = w * 16 + quad * 4 + r;
            lds[rl * 136 + c * 16 + lr] = f2bf(acc[c][r]);
        }
    }
    __syncthreads();
#pragma unroll
    for (int j = 0; j < 4; j++) {
        int idx = t + j * 256;                   // 1024 slots = 64 rows x 16 uint4
        int rl = idx >> 4, sl = idx & 15;
        int grow = blockIdx.x * 64 + rl;
        if (grow < n) {
            uint4 v = *(const uint4*)&lds[rl * 136 + sl * 8];
            ((uint4*)(H + (size_t)grow * DIM))[sl] = v;
        }
    }
}

// ---------------- CSR aggregation: 16 lanes/node, uint4 gathers, 4-edge unroll --------

#define AGG_BODY                                                                 \
    const ushort* Hl = H + lane * 8;                                             \
    float dn = dis[node];                                                        \
    int beg = row_ptr[node], end = row_ptr[node + 1];                            \
    uint4 pw = *(const uint4*)(Hl + (size_t)node * DIM);                         \
    a0 = dn * bflo(pw.x); a1 = dn * bfhi(pw.x);                                  \
    a2 = dn * bflo(pw.y); a3 = dn * bfhi(pw.y);                                  \
    a4 = dn * bflo(pw.z); a5 = dn * bfhi(pw.z);                                  \
    a6 = dn * bflo(pw.w); a7 = dn * bfhi(pw.w);                                  \
    int e = beg;                                                                 \
    for (; e + 3 < end; e += 4) {                                                \
        int c0 = col[e], c1 = col[e + 1], c2 = col[e + 2], c3 = col[e + 3];      \
        float w0 = dis[c0], w1 = dis[c1], w2 = dis[c2], w3 = dis[c3];            \
        uint4 p0 = *(const uint4*)(Hl + (size_t)c0 * DIM);                       \
        uint4 p1 = *(const uint4*)(Hl + (size_t)c1 * DIM);                       \
        uint4 p2 = *(const uint4*)(Hl + (size_t)c2 * DIM);                       \
        uint4 p3 = *(const uint4*)(Hl + (size_t)c3 * DIM);                       \
        a0 += w0 * bflo(p0.x) + w1 * bflo(p1.x) + w2 * bflo(p2.x) + w3 * bflo(p3.x); \
        a1 += w0 * bfhi(p0.x) + w1 * bfhi(p1.x) + w2 * bfhi(p2.x) + w3 * bfhi(p3.x); \
        a2 += w0 * bflo(p0.y) + w1 * bflo(p1.y) + w2 * bflo(p2.y) + w3 * bflo(p3.y); \
        a3 += w0 * bfhi(p0.y) + w1 * bfhi(p1.y) + w2 * bfhi(p2.y) + w3 * bfhi(p3.y); \
        a4 += w0 * bflo(p0.z) + w1 * bflo(p1.z) + w2 * bflo(p2.z) + w3 * bflo(p3.z); \
        a5 += w0 * bfhi(p0.z) + w1 * bfhi(p1.z) + w2 * bfhi(p2.z) + w3 * bfhi(p3.z); \
        a6 += w0 * bflo(p0.w) + w1 * bflo(p1.w) + w2 * bflo(p2.w) + w3 * bflo(p3.w); \
        a7 += w0 * bfhi(p0.w) + w1 * bfhi(p1.w) + w2 * bfhi(p2.w) + w3 * bfhi(p3.w); \
    }                                                                            \
    for (; e < end; e++) {                                                       \
        int c = col[e];                                                          \
        float w = dis[c];                                                        \
        uint4 p = *(const uint4*)(Hl + (size_t)c * DIM);                         \
        a0 += w * bflo(p.x); a1 += w * bfhi(p.x);                                \
        a2 += w * bflo(p.y); a3 += w * bfhi(p.y);                                \
        a4 += w * bflo(p.z); a5 += w * bfhi(p.z);                                \
        a6 += w * bflo(p.w); a7 += w * bfhi(p.w);                                \
    }                                                                            \
    a0 = fmaxf(a0 * dn + bias[d0], 0.f);                                         \
    a1 = fmaxf(a1 * dn + bias[d0 + 1], 0.f);                                     \
    a2 = fmaxf(a2 * dn + bias[d0 + 2], 0.f);                                     \
    a3 = fmaxf(a3 * dn + bias[d0 + 3], 0.f);                                     \
    a4 = fmaxf(a4 * dn + bias[d0 + 4], 0.f);                                     \
    a5 = fmaxf(a5 * dn + bias[d0 + 5], 0.f);                                     \
    a6 = fmaxf(a6 * dn + bias[d0 + 6], 0.f);                                     \
    a7 = fmaxf(a7 * dn + bias[d0 + 7], 0.f);

__global__ __launch_bounds__(256) void agg_k(const ushort* __restrict__ H,
                                             const int* __restrict__ row_ptr,
                                             const int* __restrict__ col,
                                             const float* __restrict__ dis,
                                             const float* __restrict__ bias,
                                             ushort* __restrict__ Out, int n) {
    int node = blockIdx.x * 16 + (threadIdx.x >> 4);
    int lane = threadIdx.x & 15;
    if (node >= n) return;
    int d0 = lane * 8;
    float a0, a1, a2, a3, a4, a5, a6, a7;
    AGG_BODY
    uint4 o;
    o.x = (uint)f2bf(a0) | ((uint)f2bf(a1) << 16);
    o.y = (uint)f2bf(a2) | ((uint)f2bf(a3) << 16);
    o.z = (uint)f2bf(a4) | ((uint)f2bf(a5) << 16);
    o.w = (uint)f2bf(a6) | ((uint)f2bf(a7) << 16);
    *(uint4*)(Out + (size_t)node * DIM + d0) = o;
}

// layer-3 agg fused with global_add_pool: LDS run-reduction over sorted batch ids,
// one global atomic per (run x feature). Final h never rounded to bf16.
__global__ __launch_bounds__(256) void agg_pool_k(const ushort* __restrict__ H,
                                                  const int* __restrict__ row_ptr,
                                                  const int* __restrict__ col,
                                                  const float* __restrict__ dis,
                                                  const float* __restrict__ bias,
                                                  const int* __restrict__ batch,
                                                  float* __restrict__ Out, int n) {
    __shared__ float acc[DIM];
    int t = threadIdx.x;
    int node = blockIdx.x * 16 + (t >> 4);
    int lane = t & 15;
    int d0 = lane * 8;
    float a0 = 0.f, a1 = 0.f, a2 = 0.f, a3 = 0.f, a4 = 0.f, a5 = 0.f, a6 = 0.f, a7 = 0.f;
    int g = -1;
    if (node < n) {
        AGG_BODY
        g = batch[node];
    }
    int first = blockIdx.x * 16;                       // always < n (grid = ceil(n/16))
    int last = first + 15 < n ? first + 15 : n - 1;
    int g0 = batch[first], g1 = batch[last];
    for (int gr = g0; gr <= g1; gr++) {
        if (t < DIM) acc[t] = 0.f;
        __syncthreads();
        if (g == gr) {
            atomicAdd(&acc[d0], a0);
            atomicAdd(&acc[d0 + 1], a1);
            atomicAdd(&acc[d0 + 2], a2);
            atomicAdd(&acc[d0 + 3], a3);
            atomicAdd(&acc[d0 + 4], a4);
            atomicAdd(&acc[d0 + 5], a5);
            atomicAdd(&acc[d0 + 6], a6);
            atomicAdd(&acc[d0 + 7], a7);
        }
        __syncthreads();
        if (t < DIM) atomicAdd(&Out[gr * DIM + t], acc[t]);
        __syncthreads();
    }
}

// ---------------- launch ----------------

extern "C" void kernel_launch(void* const* d_in, const int* in_sizes, int n_in,
                              void* d_out, int out_size, void* d_ws, size_t ws_size,
                              hipStream_t stream) {
    const float* x  = (const float*)d_in[0];
    const float* W1 = (const float*)d_in[1];
    const float* b1 = (const float*)d_in[2];
    const float* W2 = (const float*)d_in[3];
    const float* b2 = (const float*)d_in[4];
    const float* W3 = (const float*)d_in[5];
    const float* b3 = (const float*)d_in[6];
    const int*   ei = (const int*)d_in[7];
    const int*   bv = (const int*)d_in[8];
    float* out = (float*)d_out;

    const int N = N_NODES, E = N_EDGES;

    char* p = (char*)d_ws;
    auto alloc = [&](size_t bytes) -> void* {
        void* r = (void*)p;
        p += (bytes + 255) & ~(size_t)255;
        return r;
    };
    int*    bcnt_pad = (int*)alloc((size_t)NB * 16 * 4);
    int*    bcur_pad = (int*)alloc((size_t)NB * 16 * 4);
    int*    bbase    = (int*)alloc((size_t)(NB + 1) * 4);
    int*    row_ptr  = (int*)alloc((size_t)(N + 1) * 4);
    float*  dis      = (float*)alloc((size_t)N * 4);
    uint*   stage    = (uint*)alloc((size_t)E * 4);
    int*    col      = (int*)alloc((size_t)E * 4);
    ushort* B1       = (ushort*)alloc((size_t)N_PAD * DIM * 2);
    ushort* B2       = (ushort*)alloc((size_t)N_PAD * DIM * 2);

    // W buffers overlaid on stage (dead after csr_k; wconv runs after it in-stream)
    ushort* Whi = (ushort*)stage;                        // 3 * 16384
    ushort* Wlo = Whi + (size_t)3 * DIM * DIM;

    const int* src = ei;
    const int* dst = ei + E;

    hipMemsetAsync(d_out, 0, (size_t)N_GRAPHS * DIM * sizeof(float), stream);
    hipMemsetAsync(bcnt_pad, 0, (size_t)NB * 16 * 4, stream);

    bhist_k<<<NCHUNK, 256, 0, stream>>>(dst, bcnt_pad, E);
    bscan_k<<<1, 128, 0, stream>>>(bcnt_pad, bbase, bcur_pad);
    bscat_k<<<NCHUNK, 256, 0, stream>>>(src, dst, bcur_pad, stage, E);
    csr_k<<<NB, 256, 0, stream>>>(stage, bbase, row_ptr, dis, col);

    wconv_k<<<192, 256, 0, stream>>>(W1, W2, W3, Whi, Wlo);

    int gemm_grid = N_PAD / 64;          // 782
    int agg_grid  = (N + 15) / 16;

    gemm_mfma_k<float><<<gemm_grid, 256, 0, stream>>>(x, Whi, Wlo, B1, N);
    agg_k<<<agg_grid, 256, 0, stream>>>(B1, row_ptr, col, dis, b1, B2, N);

    gemm_mfma_k<ushort><<<gemm_grid, 256, 0, stream>>>(B2, Whi + (size_t)DIM * DIM,
                                                       Wlo + (size_t)DIM * DIM, B1, N);
    agg_k<<<agg_grid, 256, 0, stream>>>(B1, row_ptr, col, dis, b2, B2, N);

    gemm_mfma_k<ushort><<<gemm_grid, 256, 0, stream>>>(B2, Whi + (size_t)2 * DIM * DIM,
                                                       Wlo + (size_t)2 * DIM * DIM, B1, N);
    agg_pool_k<<<agg_grid, 256, 0, stream>>>(B1, row_ptr, col, dis, b3, bv, out, N);
}